// Round 2
// baseline (682.474 us; speedup 1.0000x reference)
//
#include <hip/hip_runtime.h>
#include <math.h>

#define BATCH 16384
#define NCLS  8192
#define NTAIL 16

// ws layout: [0, BATCH*4)            p_true  (float[BATCH])
//            [BATCH*4, BATCH*4+64)   tail counts (int[NTAIL])

__global__ void init_kernel(float* __restrict__ out, int* __restrict__ counts) {
    int t = threadIdx.x;
    if (t < NTAIL) counts[t] = 0;
    if (t == 0)    out[0] = 0.0f;
}

// One block (256 threads = 4 waves) per row. Each thread holds its full
// 32-element row slice in registers: load-all, then branch-free max/argmax
// pass, then 32 INDEPENDENT exps (no serial online-softmax chain, no
// exec-mask divergence — the R1 bottleneck).
__global__ __launch_bounds__(256) void row_kernel(const float* __restrict__ x,
                                                  const int* __restrict__ labels,
                                                  float* __restrict__ p_true,
                                                  int* __restrict__ counts) {
    const int row = blockIdx.x;
    const int t   = threadIdx.x;
    const float4* rowp = (const float4*)(x + (size_t)row * NCLS);

    float4 v[8];
    #pragma unroll
    for (int k = 0; k < 8; ++k) v[k] = rowp[t + k * 256];

    float e[32];
    #pragma unroll
    for (int k = 0; k < 8; ++k) {
        e[4 * k + 0] = v[k].x; e[4 * k + 1] = v[k].y;
        e[4 * k + 2] = v[k].z; e[4 * k + 3] = v[k].w;
    }
    #pragma unroll
    for (int i = 0; i < 32; ++i) e[i] = (e[i] == e[i]) ? e[i] : 0.0f;  // nan_to_num

    // Pass 1: thread-local max + first-occurrence argmax.
    // Column of e[i] is (t + (i>>2)*256)*4 + (i&3) — ascending in i, so
    // strict > keeps the lowest column on ties.
    float m = e[0];
    int   idx = t * 4;
    #pragma unroll
    for (int i = 1; i < 32; ++i) {
        const int col = (t + (i >> 2) * 256) * 4 + (i & 3);
        if (e[i] > m) { m = e[i]; idx = col; }
    }

    // Pass 2: 32 independent exps, 4 accumulators for ILP.
    const float L2E = 1.4426950408889634f;
    float s0 = 0.f, s1 = 0.f, s2 = 0.f, s3 = 0.f;
    #pragma unroll
    for (int i = 0; i < 32; i += 4) {
        s0 += exp2f((e[i + 0] - m) * L2E);
        s1 += exp2f((e[i + 1] - m) * L2E);
        s2 += exp2f((e[i + 2] - m) * L2E);
        s3 += exp2f((e[i + 3] - m) * L2E);
    }
    float s = (s0 + s1) + (s2 + s3);

    // wave(64)-level reduce of (m, idx, s)
    #pragma unroll
    for (int off = 32; off; off >>= 1) {
        float m2 = __shfl_down(m, off);
        float s2r = __shfl_down(s, off);
        int   i2 = __shfl_down(idx, off);
        if (m2 > m)       { s = s * exp2f((m - m2) * L2E) + s2r; m = m2; idx = i2; }
        else if (m2 == m) { s += s2r; idx = min(idx, i2); }
        else              { s += s2r * exp2f((m2 - m) * L2E); }
    }

    __shared__ float sm[4], ss[4];
    __shared__ int   si[4];
    const int wave = t >> 6;
    if ((t & 63) == 0) { sm[wave] = m; ss[wave] = s; si[wave] = idx; }
    __syncthreads();

    if (t == 0) {
        for (int wgi = 1; wgi < 4; ++wgi) {
            float m2 = sm[wgi], s2r = ss[wgi]; int i2 = si[wgi];
            if (m2 > m)       { s = s * exp2f((m - m2) * L2E) + s2r; m = m2; idx = i2; }
            else if (m2 == m) { s += s2r; idx = min(idx, i2); }
            else              { s += s2r * exp2f((m2 - m) * L2E); }
        }
        const int lab = labels[row];
        float xt = x[(size_t)row * NCLS + lab];
        xt = (xt == xt) ? xt : 0.0f;
        p_true[row] = exp2f((xt - m) * L2E) / s;
        if (idx >= NCLS - NTAIL) atomicAdd(&counts[idx - (NCLS - NTAIL)], 1);
    }
}

__global__ __launch_bounds__(256) void penalty_kernel(const float* __restrict__ p_true,
                                                      const int* __restrict__ labels,
                                                      const int* __restrict__ prev_counts,
                                                      const int* __restrict__ counts,
                                                      float* __restrict__ out) {
    const int i = blockIdx.x * 256 + threadIdx.x;
    const float p = p_true[i];
    const int lab = labels[i];
    float w = 1.0f;
    if (lab >= NCLS - NTAIL) {
        const int prev = prev_counts[lab];
        const int curr = counts[lab - (NCLS - NTAIL)];
        w = (prev > 0 && curr < prev) ? 4.0f
          : (prev > 0 && curr > prev) ? 2.0f
          : 3.0f;
    }
    float pen = -logf(p + 1e-7f) * (1.0f - p) * w;

    #pragma unroll
    for (int off = 32; off; off >>= 1) pen += __shfl_down(pen, off);

    __shared__ float acc[4];
    if ((threadIdx.x & 63) == 0) acc[threadIdx.x >> 6] = pen;
    __syncthreads();
    if (threadIdx.x == 0) {
        const float bs = acc[0] + acc[1] + acc[2] + acc[3];
        atomicAdd(out, bs * (0.1f / (float)BATCH));
    }
}

extern "C" void kernel_launch(void* const* d_in, const int* in_sizes, int n_in,
                              void* d_out, int out_size, void* d_ws, size_t ws_size,
                              hipStream_t stream) {
    const float* x           = (const float*)d_in[0];
    const int*   labels      = (const int*)  d_in[1];
    const int*   prev_counts = (const int*)  d_in[2];
    // d_in[3] (tail_mask) is deterministic: class >= NCLS-NTAIL — recomputed inline.

    float* out    = (float*)d_out;
    float* p_true = (float*)d_ws;
    int*   counts = (int*)((char*)d_ws + BATCH * sizeof(float));

    init_kernel<<<1, 64, 0, stream>>>(out, counts);
    row_kernel<<<BATCH, 256, 0, stream>>>(x, labels, p_true, counts);
    penalty_kernel<<<BATCH / 256, 256, 0, stream>>>(p_true, labels, prev_counts, counts, out);
}